// Round 1
// baseline (1541.410 us; speedup 1.0000x reference)
//
#include <hip/hip_runtime.h>

#define N_NODES 100000
#define N_EDGES 3200000
#define SLOPE 0.01f

static inline size_t align_up(size_t x, size_t a){ return (x + a - 1) / a * a; }

// ---------------- CSR build ----------------

__global__ void hist_k(const int* __restrict__ dst, int* __restrict__ counts){
  int e = blockIdx.x * 256 + threadIdx.x;
  if (e < N_EDGES) atomicAdd(&counts[dst[e]], 1);
}

// 1024 elements per block (256 threads x 4), exclusive scan within block
__global__ void scan_block_k(const int* __restrict__ counts, int* __restrict__ out,
                             int* __restrict__ bsums){
  __shared__ int lds[256];
  int tid = threadIdx.x;
  int base = blockIdx.x * 1024 + tid * 4;
  int v0 = (base + 0 < N_NODES) ? counts[base + 0] : 0;
  int v1 = (base + 1 < N_NODES) ? counts[base + 1] : 0;
  int v2 = (base + 2 < N_NODES) ? counts[base + 2] : 0;
  int v3 = (base + 3 < N_NODES) ? counts[base + 3] : 0;
  int tsum = v0 + v1 + v2 + v3;
  lds[tid] = tsum;
  for (int off = 1; off < 256; off <<= 1){
    __syncthreads();
    int x = (tid >= off) ? lds[tid - off] : 0;
    __syncthreads();
    lds[tid] += x;
  }
  __syncthreads();
  int excl = lds[tid] - tsum;   // exclusive prefix of this thread's 4-chunk
  if (base + 0 < N_NODES) out[base + 0] = excl;
  if (base + 1 < N_NODES) out[base + 1] = excl + v0;
  if (base + 2 < N_NODES) out[base + 2] = excl + v0 + v1;
  if (base + 3 < N_NODES) out[base + 3] = excl + v0 + v1 + v2;
  if (tid == 255) bsums[blockIdx.x] = lds[255];
}

__global__ void scan_sums_k(int* bsums, int nb){
  if (threadIdx.x == 0 && blockIdx.x == 0){
    int acc = 0;
    for (int i = 0; i < nb; i++){ int t = bsums[i]; bsums[i] = acc; acc += t; }
  }
}

__global__ void finalize_k(int* __restrict__ row_ptr, int* __restrict__ cursor,
                           const int* __restrict__ bsums){
  int i = blockIdx.x * 256 + threadIdx.x;
  if (i < N_NODES){
    int v = row_ptr[i] + bsums[i >> 10];
    row_ptr[i] = v;
    cursor[i]  = v;
  } else if (i == N_NODES){
    row_ptr[N_NODES] = N_EDGES;
  }
}

__global__ void scatter_k(const int* __restrict__ src, const int* __restrict__ dst,
                          int* __restrict__ cursor, int* __restrict__ ssrc){
  int e = blockIdx.x * 256 + threadIdx.x;
  if (e < N_EDGES){
    int p = atomicAdd(&cursor[dst[e]], 1);
    ssrc[p] = src[e];
  }
}

// ---------------- Layer 1: feat[N,4] -> lrelu(agg @ W1 + b1) [N,64] ----------------
// one wave per node; lane handles (neighbor-slot = lane>>2, channel = lane&3)
__global__ void conv1_k(const float* __restrict__ feat, const int* __restrict__ row_ptr,
                        const int* __restrict__ ssrc, const float* __restrict__ W1,
                        const float* __restrict__ b1, float* __restrict__ out){
  int gt = blockIdx.x * 256 + threadIdx.x;
  int node = gt >> 6;
  int lane = threadIdx.x & 63;
  if (node >= N_NODES) return;
  int s = row_ptr[node], t = row_ptr[node + 1];
  int c = lane & 3;
  float acc = 0.f;
  for (int i = s + (lane >> 2); i < t; i += 16){
    int nb = ssrc[i];
    acc += feat[nb * 4 + c];
  }
  // reduce over the 16 lanes sharing the same channel (xor over bits 2..5)
  for (int m = 4; m < 64; m <<= 1) acc += __shfl_xor(acc, m);
  float a0 = __shfl(acc, 0), a1 = __shfl(acc, 1), a2 = __shfl(acc, 2), a3 = __shfl(acc, 3);
  float o = b1[lane] + a0 * W1[lane] + a1 * W1[64 + lane] + a2 * W1[128 + lane] + a3 * W1[192 + lane];
  out[node * 64 + lane] = (o > 0.f) ? o : SLOPE * o;
}

// ---------------- Mid layers: x[N,64] -> lrelu(agg @ W2 + b2) [N,64] ----------------
// one wave per node, lane = channel; W staged in LDS once per block
__global__ void conv64_k(const float* __restrict__ x, const int* __restrict__ row_ptr,
                         const int* __restrict__ ssrc, const float* __restrict__ W,
                         const float* __restrict__ b, float* __restrict__ out){
  __shared__ float sW[4096];
  __shared__ float sAgg[4][64];
  int tid = threadIdx.x;
  for (int i = tid; i < 4096; i += 256) sW[i] = W[i];
  __syncthreads();
  int w = tid >> 6, lane = tid & 63;
  int node = blockIdx.x * 4 + w;
  if (node >= N_NODES) return;
  int s = row_ptr[node], t = row_ptr[node + 1];
  float acc = 0.f;
  int i = s;
  for (; i + 4 <= t; i += 4){
    int n0 = ssrc[i], n1 = ssrc[i + 1], n2 = ssrc[i + 2], n3 = ssrc[i + 3];
    float x0 = x[n0 * 64 + lane];
    float x1 = x[n1 * 64 + lane];
    float x2 = x[n2 * 64 + lane];
    float x3 = x[n3 * 64 + lane];
    acc += x0 + x1 + x2 + x3;
  }
  for (; i < t; ++i) acc += x[ssrc[i] * 64 + lane];
  sAgg[w][lane] = acc;            // wave-local LDS, no barrier needed
  float o = b[lane];
  #pragma unroll 8
  for (int k = 0; k < 64; ++k) o += sAgg[w][k] * sW[k * 64 + lane];
  out[node * 64 + lane] = (o > 0.f) ? o : SLOPE * o;
}

// ---------------- Last layer: y = x @ W5 [N,3], then agg + b5 ----------------
__global__ void premult_k(const float* __restrict__ x, const float* __restrict__ W5,
                          float* __restrict__ y){
  int gt = blockIdx.x * 256 + threadIdx.x;
  int node = gt >> 6;
  int lane = threadIdx.x & 63;
  if (node >= N_NODES) return;
  float xv = x[node * 64 + lane];
  float p0 = xv * W5[lane * 3 + 0];
  float p1 = xv * W5[lane * 3 + 1];
  float p2 = xv * W5[lane * 3 + 2];
  for (int m = 1; m < 64; m <<= 1){
    p0 += __shfl_xor(p0, m);
    p1 += __shfl_xor(p1, m);
    p2 += __shfl_xor(p2, m);
  }
  if (lane == 0){
    y[node * 3 + 0] = p0;
    y[node * 3 + 1] = p1;
    y[node * 3 + 2] = p2;
  }
}

__global__ void agg3_k(const float* __restrict__ y, const int* __restrict__ row_ptr,
                       const int* __restrict__ ssrc, const float* __restrict__ b5,
                       float* __restrict__ out){
  int gt = blockIdx.x * 256 + threadIdx.x;
  int node = gt >> 6;
  int lane = threadIdx.x & 63;
  if (node >= N_NODES) return;
  int s = row_ptr[node], t = row_ptr[node + 1];
  int c = lane & 3;
  float acc = 0.f;
  if (c < 3){
    for (int i = s + (lane >> 2); i < t; i += 16) acc += y[ssrc[i] * 3 + c];
  }
  for (int m = 4; m < 64; m <<= 1) acc += __shfl_xor(acc, m);
  if (lane < 3) out[node * 3 + lane] = acc + b5[lane];
}

// ---------------- launch ----------------

extern "C" void kernel_launch(void* const* d_in, const int* in_sizes, int n_in,
                              void* d_out, int out_size, void* d_ws, size_t ws_size,
                              hipStream_t stream){
  const float* feat = (const float*)d_in[0];
  const int*   src  = (const int*)d_in[1];
  const int*   dst  = (const int*)d_in[2];
  const float* W1   = (const float*)d_in[3];
  const float* b1   = (const float*)d_in[4];
  const float* W2   = (const float*)d_in[5];
  const float* b2   = (const float*)d_in[6];
  const float* W5   = (const float*)d_in[7];
  const float* b5   = (const float*)d_in[8];
  float* out = (float*)d_out;

  char* p = (char*)d_ws;
  auto carve = [&](size_t bytes) -> char* {
    char* r = p; p += align_up(bytes, 512); return r;
  };
  int*   counts  = (int*)carve((size_t)N_NODES * 4);
  int*   row_ptr = (int*)carve((size_t)(N_NODES + 1) * 4);
  int*   cursor  = (int*)carve((size_t)N_NODES * 4);
  int*   bsums   = (int*)carve(128 * 4);
  int*   ssrc    = (int*)carve((size_t)N_EDGES * 4);
  float* bufA    = (float*)carve((size_t)N_NODES * 64 * 4);
  float* bufB    = (float*)carve((size_t)N_NODES * 64 * 4);
  float* y3      = (float*)carve((size_t)N_NODES * 3 * 4);

  hipMemsetAsync(counts, 0, (size_t)N_NODES * 4, stream);

  hist_k<<<(N_EDGES + 255) / 256, 256, 0, stream>>>(dst, counts);
  int nsb = (N_NODES + 1023) / 1024; // 98
  scan_block_k<<<nsb, 256, 0, stream>>>(counts, row_ptr, bsums);
  scan_sums_k<<<1, 64, 0, stream>>>(bsums, nsb);
  finalize_k<<<(N_NODES + 1 + 255) / 256, 256, 0, stream>>>(row_ptr, cursor, bsums);
  scatter_k<<<(N_EDGES + 255) / 256, 256, 0, stream>>>(src, dst, cursor, ssrc);

  conv1_k<<<(N_NODES * 64 + 255) / 256, 256, 0, stream>>>(feat, row_ptr, ssrc, W1, b1, bufA);

  float* xin = bufA;
  float* xout = bufB;
  for (int l = 0; l < 7; ++l){
    conv64_k<<<(N_NODES + 3) / 4, 256, 0, stream>>>(xin, row_ptr, ssrc, W2, b2, xout);
    float* tmp = xin; xin = xout; xout = tmp;
  }

  premult_k<<<(N_NODES * 64 + 255) / 256, 256, 0, stream>>>(xin, W5, y3);
  agg3_k<<<(N_NODES * 64 + 255) / 256, 256, 0, stream>>>(y3, row_ptr, ssrc, b5, out);
}

// Round 2
// 1207.160 us; speedup vs baseline: 1.2769x; 1.2769x over previous
//
#include <hip/hip_runtime.h>

#define N_NODES 100000
#define N_EDGES 3200000
#define SLOPE 0.01f

#define NBUCK 391              // ceil(100000/256) buckets of 256 dst nodes
#define NGRP 16                // blockIdx&15 groups (XCD-locality proxy)
#define NBLK_AB 2048
#define EPB ((N_EDGES + NBLK_AB - 1) / NBLK_AB)   // 1563 edges per block

static inline size_t align_up(size_t x, size_t a){ return (x + a - 1) / a * a; }

// ---------------- CSR build: bucketed 2-pass ----------------

// Pass A: per-(bucket,group) histogram. Block's group = blockIdx&15.
__global__ void gbhist_k(const int* __restrict__ dst, int* __restrict__ ghist){
  __shared__ int h[NBUCK];
  int tid = threadIdx.x;
  for (int i = tid; i < NBUCK; i += 256) h[i] = 0;
  __syncthreads();
  int g = blockIdx.x & (NGRP - 1);
  int e0 = blockIdx.x * EPB;
  int end = min(e0 + EPB, N_EDGES);
  for (int e = e0 + tid; e < end; e += 256) atomicAdd(&h[dst[e] >> 8], 1);
  __syncthreads();
  for (int i = tid; i < NBUCK; i += 256){
    int v = h[i];
    if (v) atomicAdd(&ghist[i * NGRP + g], v);
  }
}

// exclusive scan of ghist[NBUCK*NGRP] -> goff and gcur (single block)
__global__ void scan_gb_k(const int* __restrict__ ghist, int* __restrict__ goff,
                          int* __restrict__ gcur){
  __shared__ int lds[256];
  const int n = NBUCK * NGRP;
  const int chunk = (n + 255) / 256;
  int tid = threadIdx.x;
  int b0 = tid * chunk;
  int sum = 0;
  for (int i = 0; i < chunk; ++i){ int idx = b0 + i; if (idx < n) sum += ghist[idx]; }
  lds[tid] = sum;
  for (int off = 1; off < 256; off <<= 1){
    __syncthreads();
    int x = (tid >= off) ? lds[tid - off] : 0;
    __syncthreads();
    lds[tid] += x;
  }
  __syncthreads();
  int run = lds[tid] - sum;
  for (int i = 0; i < chunk; ++i){
    int idx = b0 + i;
    if (idx < n){ int v = ghist[idx]; goff[idx] = run; gcur[idx] = run; run += v; }
  }
}

// Pass B: scatter packed (src<<8 | dst&255) into bucket-major, group-sub order.
__global__ void passB_k(const int* __restrict__ src, const int* __restrict__ dst,
                        int* __restrict__ gcur, int* __restrict__ pk){
  int g = blockIdx.x & (NGRP - 1);
  int e0 = blockIdx.x * EPB;
  int end = min(e0 + EPB, N_EDGES);
  for (int e = e0 + threadIdx.x; e < end; e += 256){
    int d = dst[e];
    int pos = atomicAdd(&gcur[(d >> 8) * NGRP + g], 1);
    pk[pos] = (src[e] << 8) | (d & 255);
  }
}

// node-degree counts from bucket-major packed edges (no global atomics)
__global__ void histnode_k(const int* __restrict__ pk, const int* __restrict__ goff,
                           int* __restrict__ counts){
  __shared__ int cnt[256];
  int b = blockIdx.x, tid = threadIdx.x;
  cnt[tid] = 0;
  __syncthreads();
  int s = goff[b * NGRP];
  int e = (b == NBUCK - 1) ? N_EDGES : goff[(b + 1) * NGRP];
  for (int i = s + tid; i < e; i += 256) atomicAdd(&cnt[pk[i] & 255], 1);
  __syncthreads();
  int node = b * 256 + tid;
  if (node < N_NODES) counts[node] = cnt[tid];
}

// 1024 elements per block (256 threads x 4), exclusive scan within block
__global__ void scan_block_k(const int* __restrict__ counts, int* __restrict__ out,
                             int* __restrict__ bsums){
  __shared__ int lds[256];
  int tid = threadIdx.x;
  int base = blockIdx.x * 1024 + tid * 4;
  int v0 = (base + 0 < N_NODES) ? counts[base + 0] : 0;
  int v1 = (base + 1 < N_NODES) ? counts[base + 1] : 0;
  int v2 = (base + 2 < N_NODES) ? counts[base + 2] : 0;
  int v3 = (base + 3 < N_NODES) ? counts[base + 3] : 0;
  int tsum = v0 + v1 + v2 + v3;
  lds[tid] = tsum;
  for (int off = 1; off < 256; off <<= 1){
    __syncthreads();
    int x = (tid >= off) ? lds[tid - off] : 0;
    __syncthreads();
    lds[tid] += x;
  }
  __syncthreads();
  int excl = lds[tid] - tsum;
  if (base + 0 < N_NODES) out[base + 0] = excl;
  if (base + 1 < N_NODES) out[base + 1] = excl + v0;
  if (base + 2 < N_NODES) out[base + 2] = excl + v0 + v1;
  if (base + 3 < N_NODES) out[base + 3] = excl + v0 + v1 + v2;
  if (tid == 255) bsums[blockIdx.x] = lds[255];
}

__global__ void scan_sums_k(int* bsums, int nb){
  if (threadIdx.x == 0 && blockIdx.x == 0){
    int acc = 0;
    for (int i = 0; i < nb; i++){ int t = bsums[i]; bsums[i] = acc; acc += t; }
  }
}

__global__ void finalize_k(int* __restrict__ row_ptr, const int* __restrict__ bsums){
  int i = blockIdx.x * 256 + threadIdx.x;
  if (i < N_NODES){
    row_ptr[i] += bsums[i >> 10];
  } else if (i == N_NODES){
    row_ptr[N_NODES] = N_EDGES;
  }
}

// Pass C: final within-bucket scatter, LDS cursors, writes land in a 32KB window
__global__ void passC_k(const int* __restrict__ pk, const int* __restrict__ goff,
                        const int* __restrict__ row_ptr, int* __restrict__ ssrc){
  __shared__ int cur[256];
  int b = blockIdx.x, tid = threadIdx.x;
  int node = b * 256 + tid;
  if (node < N_NODES) cur[tid] = row_ptr[node];
  __syncthreads();
  int s = goff[b * NGRP];
  int e = (b == NBUCK - 1) ? N_EDGES : goff[(b + 1) * NGRP];
  for (int i = s + tid; i < e; i += 256){
    int v = pk[i];
    int p = atomicAdd(&cur[v & 255], 1);
    ssrc[p] = v >> 8;
  }
}

// ---------------- Layer 1: feat[N,4] -> lrelu(agg @ W1 + b1) [N,64] ----------------
// one wave per node; each lane loads a whole 16B row (float4)
__global__ void conv1_k(const float* __restrict__ feat, const int* __restrict__ row_ptr,
                        const int* __restrict__ ssrc, const float* __restrict__ W1,
                        const float* __restrict__ b1, float* __restrict__ out){
  int gt = blockIdx.x * 256 + threadIdx.x;
  int node = gt >> 6;
  int lane = threadIdx.x & 63;
  if (node >= N_NODES) return;
  int s = row_ptr[node], t = row_ptr[node + 1];
  float a0 = 0.f, a1 = 0.f, a2 = 0.f, a3 = 0.f;
  for (int i = s + lane; i < t; i += 64){
    int nb = ssrc[i];
    const float4 v = *(const float4*)(feat + (size_t)nb * 4);
    a0 += v.x; a1 += v.y; a2 += v.z; a3 += v.w;
  }
  for (int m = 1; m < 64; m <<= 1){
    a0 += __shfl_xor(a0, m);
    a1 += __shfl_xor(a1, m);
    a2 += __shfl_xor(a2, m);
    a3 += __shfl_xor(a3, m);
  }
  float o = b1[lane] + a0 * W1[lane] + a1 * W1[64 + lane] + a2 * W1[128 + lane] + a3 * W1[192 + lane];
  out[node * 64 + lane] = (o > 0.f) ? o : SLOPE * o;
}

// ---------------- Mid layers: x[N,64] -> lrelu(agg @ W2 + b2) [N,64] ----------------
// one wave per node; lane loads float4 quarter-rows: 4 rows (16 lines) per instr
__global__ void conv64_k(const float* __restrict__ x, const int* __restrict__ row_ptr,
                         const int* __restrict__ ssrc, const float* __restrict__ W,
                         const float* __restrict__ b, float* __restrict__ out){
  __shared__ float sW[4096];
  __shared__ float sAgg[4][64];
  int tid = threadIdx.x;
  for (int i = tid; i < 4096; i += 256) sW[i] = W[i];
  __syncthreads();
  int w = tid >> 6, lane = tid & 63;
  int node = blockIdx.x * 4 + w;          // grid covers exactly N_NODES
  int s = row_ptr[node], t = row_ptr[node + 1];
  int cnt = t - s;
  int q = lane >> 4;          // which of 4 neighbor slots
  int o = lane & 15;          // which float4 chunk of the row
  float a0 = 0.f, a1 = 0.f, a2 = 0.f, a3 = 0.f;
  int i = 0;
  for (; i + 8 <= cnt; i += 8){
    int nb0 = ssrc[s + i + q];
    int nb1 = ssrc[s + i + 4 + q];
    const float4 v0 = *(const float4*)(x + (size_t)nb0 * 64 + (o << 2));
    const float4 v1 = *(const float4*)(x + (size_t)nb1 * 64 + (o << 2));
    a0 += v0.x; a1 += v0.y; a2 += v0.z; a3 += v0.w;
    a0 += v1.x; a1 += v1.y; a2 += v1.z; a3 += v1.w;
  }
  for (; i < cnt; i += 4){
    int j = i + q;
    if (j < cnt){
      int nb = ssrc[s + j];
      const float4 v = *(const float4*)(x + (size_t)nb * 64 + (o << 2));
      a0 += v.x; a1 += v.y; a2 += v.z; a3 += v.w;
    }
  }
  // combine the 4 neighbor slots (lanes sharing `o` across q): xor over bits 4,5
  for (int m = 16; m < 64; m <<= 1){
    a0 += __shfl_xor(a0, m);
    a1 += __shfl_xor(a1, m);
    a2 += __shfl_xor(a2, m);
    a3 += __shfl_xor(a3, m);
  }
  if (lane < 16){
    sAgg[w][lane * 4 + 0] = a0;
    sAgg[w][lane * 4 + 1] = a1;
    sAgg[w][lane * 4 + 2] = a2;
    sAgg[w][lane * 4 + 3] = a3;
  }
  float acc = b[lane];
  #pragma unroll 8
  for (int k = 0; k < 64; ++k) acc += sAgg[w][k] * sW[k * 64 + lane];
  out[node * 64 + lane] = (acc > 0.f) ? acc : SLOPE * acc;
}

// ---------------- Last layer: y = x @ W5 [N,3], then agg + b5 ----------------
__global__ void premult_k(const float* __restrict__ x, const float* __restrict__ W5,
                          float* __restrict__ y){
  int gt = blockIdx.x * 256 + threadIdx.x;
  int node = gt >> 6;
  int lane = threadIdx.x & 63;
  if (node >= N_NODES) return;
  float xv = x[node * 64 + lane];
  float p0 = xv * W5[lane * 3 + 0];
  float p1 = xv * W5[lane * 3 + 1];
  float p2 = xv * W5[lane * 3 + 2];
  for (int m = 1; m < 64; m <<= 1){
    p0 += __shfl_xor(p0, m);
    p1 += __shfl_xor(p1, m);
    p2 += __shfl_xor(p2, m);
  }
  if (lane == 0){
    y[node * 3 + 0] = p0;
    y[node * 3 + 1] = p1;
    y[node * 3 + 2] = p2;
  }
}

__global__ void agg3_k(const float* __restrict__ y, const int* __restrict__ row_ptr,
                       const int* __restrict__ ssrc, const float* __restrict__ b5,
                       float* __restrict__ out){
  int gt = blockIdx.x * 256 + threadIdx.x;
  int node = gt >> 6;
  int lane = threadIdx.x & 63;
  if (node >= N_NODES) return;
  int s = row_ptr[node], t = row_ptr[node + 1];
  int c = lane & 3;
  float acc = 0.f;
  if (c < 3){
    for (int i = s + (lane >> 2); i < t; i += 16) acc += y[(size_t)ssrc[i] * 3 + c];
  }
  for (int m = 4; m < 64; m <<= 1) acc += __shfl_xor(acc, m);
  if (lane < 3) out[node * 3 + lane] = acc + b5[lane];
}

// ---------------- launch ----------------

extern "C" void kernel_launch(void* const* d_in, const int* in_sizes, int n_in,
                              void* d_out, int out_size, void* d_ws, size_t ws_size,
                              hipStream_t stream){
  const float* feat = (const float*)d_in[0];
  const int*   src  = (const int*)d_in[1];
  const int*   dst  = (const int*)d_in[2];
  const float* W1   = (const float*)d_in[3];
  const float* b1   = (const float*)d_in[4];
  const float* W2   = (const float*)d_in[5];
  const float* b2   = (const float*)d_in[6];
  const float* W5   = (const float*)d_in[7];
  const float* b5   = (const float*)d_in[8];
  float* out = (float*)d_out;

  char* p = (char*)d_ws;
  auto carve = [&](size_t bytes) -> char* {
    char* r = p; p += align_up(bytes, 512); return r;
  };
  int*   counts  = (int*)carve((size_t)N_NODES * 4);
  int*   row_ptr = (int*)carve((size_t)(N_NODES + 1) * 4);
  int*   bsums   = (int*)carve(128 * 4);
  int*   ghist   = (int*)carve((size_t)NBUCK * NGRP * 4);
  int*   goff    = (int*)carve((size_t)NBUCK * NGRP * 4);
  int*   gcur    = (int*)carve((size_t)NBUCK * NGRP * 4);
  int*   ssrc    = (int*)carve((size_t)N_EDGES * 4);
  float* bufA    = (float*)carve((size_t)N_NODES * 64 * 4);
  float* bufB    = (float*)carve((size_t)N_NODES * 64 * 4);
  float* y3      = (float*)carve((size_t)N_NODES * 3 * 4);
  // pk (12.8MB) aliases bufB (25.6MB): pk is dead before conv64 first writes bufB
  int*   pk      = (int*)bufB;

  hipMemsetAsync(ghist, 0, (size_t)NBUCK * NGRP * 4, stream);

  gbhist_k<<<NBLK_AB, 256, 0, stream>>>(dst, ghist);
  scan_gb_k<<<1, 256, 0, stream>>>(ghist, goff, gcur);
  passB_k<<<NBLK_AB, 256, 0, stream>>>(src, dst, gcur, pk);
  histnode_k<<<NBUCK, 256, 0, stream>>>(pk, goff, counts);
  int nsb = (N_NODES + 1023) / 1024; // 98
  scan_block_k<<<nsb, 256, 0, stream>>>(counts, row_ptr, bsums);
  scan_sums_k<<<1, 64, 0, stream>>>(bsums, nsb);
  finalize_k<<<(N_NODES + 1 + 255) / 256, 256, 0, stream>>>(row_ptr, bsums);
  passC_k<<<NBUCK, 256, 0, stream>>>(pk, goff, row_ptr, ssrc);

  conv1_k<<<(N_NODES * 64) / 256, 256, 0, stream>>>(feat, row_ptr, ssrc, W1, b1, bufA);

  float* xin = bufA;
  float* xout = bufB;
  for (int l = 0; l < 7; ++l){
    conv64_k<<<N_NODES / 4, 256, 0, stream>>>(xin, row_ptr, ssrc, W2, b2, xout);
    float* tmp = xin; xin = xout; xout = tmp;
  }

  premult_k<<<(N_NODES * 64) / 256, 256, 0, stream>>>(xin, W5, y3);
  agg3_k<<<(N_NODES * 64) / 256, 256, 0, stream>>>(y3, row_ptr, ssrc, b5, out);
}

// Round 3
// 956.322 us; speedup vs baseline: 1.6118x; 1.2623x over previous
//
#include <hip/hip_runtime.h>

#define N_NODES 100000
#define N_EDGES 3200000
#define SLOPE 0.01f

#define NBUCK 391              // ceil(100000/256) buckets of 256 dst nodes
#define NBLK_B 256             // one cursor-group per block: exclusive append regions
#define EPB (N_EDGES / NBLK_B) // 12500 edges per block (exact)
#define NGH (NBUCK * NBLK_B)   // ghist/goff size = 100096

static inline size_t align_up(size_t x, size_t a){ return (x + a - 1) / a * a; }

__device__ inline unsigned short f2bf(float f){
  unsigned u = __float_as_uint(f);
  u += 0x7fffu + ((u >> 16) & 1u);
  return (unsigned short)(u >> 16);
}
__device__ inline float bf2f(unsigned short s){
  return __uint_as_float(((unsigned)s) << 16);
}
__device__ inline void add2(float& a0, float& a1, unsigned u){
  a0 += __uint_as_float(u << 16);
  a1 += __uint_as_float(u & 0xffff0000u);
}

// ---------------- CSR build: per-block exclusive bucketed 2-pass ----------------

// Pass A: per-(bucket,block) histogram, non-atomic global write.
__global__ void gbhist_k(const int* __restrict__ dst, int* __restrict__ ghist){
  __shared__ int h[NBUCK];
  int tid = threadIdx.x, blk = blockIdx.x;
  for (int i = tid; i < NBUCK; i += 256) h[i] = 0;
  __syncthreads();
  int e0 = blk * EPB;
  for (int e = e0 + tid; e < e0 + EPB; e += 256) atomicAdd(&h[dst[e] >> 8], 1);
  __syncthreads();
  for (int i = tid; i < NBUCK; i += 256) ghist[i * NBLK_B + blk] = h[i];
}

// generalized exclusive scan: 1024 elems/block
__global__ void scan1_k(const int* __restrict__ in, int* __restrict__ out,
                        int* __restrict__ bsums, int n){
  __shared__ int lds[256];
  int tid = threadIdx.x;
  int base = blockIdx.x * 1024 + tid * 4;
  int v0 = (base + 0 < n) ? in[base + 0] : 0;
  int v1 = (base + 1 < n) ? in[base + 1] : 0;
  int v2 = (base + 2 < n) ? in[base + 2] : 0;
  int v3 = (base + 3 < n) ? in[base + 3] : 0;
  int tsum = v0 + v1 + v2 + v3;
  lds[tid] = tsum;
  for (int off = 1; off < 256; off <<= 1){
    __syncthreads();
    int x = (tid >= off) ? lds[tid - off] : 0;
    __syncthreads();
    lds[tid] += x;
  }
  __syncthreads();
  int excl = lds[tid] - tsum;
  if (base + 0 < n) out[base + 0] = excl;
  if (base + 1 < n) out[base + 1] = excl + v0;
  if (base + 2 < n) out[base + 2] = excl + v0 + v1;
  if (base + 3 < n) out[base + 3] = excl + v0 + v1 + v2;
  if (tid == 255) bsums[blockIdx.x] = lds[255];
}

__global__ void scan2_k(int* bsums, int nb){
  if (threadIdx.x == 0 && blockIdx.x == 0){
    int acc = 0;
    for (int i = 0; i < nb; i++){ int t = bsums[i]; bsums[i] = acc; acc += t; }
  }
}

__global__ void scan3_k(int* __restrict__ out, const int* __restrict__ bsums,
                        int n, int set_end){
  int i = blockIdx.x * 256 + threadIdx.x;
  if (i < n) out[i] += bsums[i >> 10];
  else if (i == n && set_end) out[n] = N_EDGES;
}

// Pass B: scatter packed (src<<8 | dst&255); LDS-private cursors, exclusive regions.
__global__ void passB_k(const int* __restrict__ src, const int* __restrict__ dst,
                        const int* __restrict__ goff, int* __restrict__ pk){
  __shared__ int cur[NBUCK];
  int tid = threadIdx.x, blk = blockIdx.x;
  for (int b = tid; b < NBUCK; b += 256) cur[b] = goff[b * NBLK_B + blk];
  __syncthreads();
  int e0 = blk * EPB;
  for (int e = e0 + tid; e < e0 + EPB; e += 256){
    int d = dst[e];
    int pos = atomicAdd(&cur[d >> 8], 1);
    pk[pos] = (src[e] << 8) | (d & 255);
  }
}

// node-degree counts from bucket-major packed edges (LDS atomics only)
__global__ void histnode_k(const int* __restrict__ pk, const int* __restrict__ goff,
                           int* __restrict__ counts){
  __shared__ int cnt[256];
  int b = blockIdx.x, tid = threadIdx.x;
  cnt[tid] = 0;
  __syncthreads();
  int s = goff[b * NBLK_B];
  int e = (b == NBUCK - 1) ? N_EDGES : goff[(b + 1) * NBLK_B];
  for (int i = s + tid; i < e; i += 256) atomicAdd(&cnt[pk[i] & 255], 1);
  __syncthreads();
  int node = b * 256 + tid;
  if (node < N_NODES) counts[node] = cnt[tid];
}

// Pass C: within-bucket scatter, LDS cursors, writes land in a ~32KB window
__global__ void passC_k(const int* __restrict__ pk, const int* __restrict__ goff,
                        const int* __restrict__ row_ptr, int* __restrict__ ssrc){
  __shared__ int cur[256];
  int b = blockIdx.x, tid = threadIdx.x;
  int node = b * 256 + tid;
  if (node < N_NODES) cur[tid] = row_ptr[node];
  __syncthreads();
  int s = goff[b * NBLK_B];
  int e = (b == NBUCK - 1) ? N_EDGES : goff[(b + 1) * NBLK_B];
  for (int i = s + tid; i < e; i += 256){
    int v = pk[i];
    int p = atomicAdd(&cur[v & 255], 1);
    ssrc[p] = v >> 8;
  }
}

// ---------------- Layer 1: feat[N,4] -> lrelu(agg @ W1 + b1) -> bf16 [N,64] --------
__global__ void conv1_k(const float* __restrict__ feat, const int* __restrict__ row_ptr,
                        const int* __restrict__ ssrc, const float* __restrict__ W1,
                        const float* __restrict__ b1, unsigned short* __restrict__ out){
  int gt = blockIdx.x * 256 + threadIdx.x;
  int node = gt >> 6;
  int lane = threadIdx.x & 63;
  int s = row_ptr[node], t = row_ptr[node + 1];
  float a0 = 0.f, a1 = 0.f, a2 = 0.f, a3 = 0.f;
  for (int i = s + lane; i < t; i += 64){
    int nb = ssrc[i];
    const float4 v = *(const float4*)(feat + (size_t)nb * 4);
    a0 += v.x; a1 += v.y; a2 += v.z; a3 += v.w;
  }
  for (int m = 1; m < 64; m <<= 1){
    a0 += __shfl_xor(a0, m);
    a1 += __shfl_xor(a1, m);
    a2 += __shfl_xor(a2, m);
    a3 += __shfl_xor(a3, m);
  }
  float o = b1[lane] + a0 * W1[lane] + a1 * W1[64 + lane] + a2 * W1[128 + lane] + a3 * W1[192 + lane];
  o = (o > 0.f) ? o : SLOPE * o;
  out[node * 64 + lane] = f2bf(o);
}

// ---------------- Mid layers: bf16 x[N,64] -> lrelu(agg @ W2 + b2) -> bf16 --------
// one wave per node; lane loads uint4 (8 bf16) = 1/8 row: 8 rows (128B each) per instr
__global__ void conv64_k(const unsigned short* __restrict__ x, const int* __restrict__ row_ptr,
                         const int* __restrict__ ssrc, const float* __restrict__ W,
                         const float* __restrict__ b, unsigned short* __restrict__ out){
  __shared__ float sW[4096];
  __shared__ float sAgg[4][64];
  int tid = threadIdx.x;
  for (int i = tid; i < 4096; i += 256) sW[i] = W[i];
  __syncthreads();
  int w = tid >> 6, lane = tid & 63;
  int node = blockIdx.x * 4 + w;          // grid covers exactly N_NODES
  int s = row_ptr[node], cnt = row_ptr[node + 1] - s;
  int q = lane >> 3;          // which of 8 neighbor slots
  int o = lane & 7;           // which 16B chunk (8 channels) of the 128B row
  float a0=0.f,a1=0.f,a2=0.f,a3=0.f,a4=0.f,a5=0.f,a6=0.f,a7=0.f;
  int i = 0;
  for (; i + 8 <= cnt; i += 8){
    int nb = ssrc[s + i + q];
    const uint4 v = *(const uint4*)(x + (size_t)nb * 64 + (o << 3));
    add2(a0, a1, v.x); add2(a2, a3, v.y); add2(a4, a5, v.z); add2(a6, a7, v.w);
  }
  if (i + q < cnt){
    int nb = ssrc[s + i + q];
    const uint4 v = *(const uint4*)(x + (size_t)nb * 64 + (o << 3));
    add2(a0, a1, v.x); add2(a2, a3, v.y); add2(a4, a5, v.z); add2(a6, a7, v.w);
  }
  // combine the 8 neighbor slots (xor over bits 3,4,5)
  for (int m = 8; m < 64; m <<= 1){
    a0 += __shfl_xor(a0, m); a1 += __shfl_xor(a1, m);
    a2 += __shfl_xor(a2, m); a3 += __shfl_xor(a3, m);
    a4 += __shfl_xor(a4, m); a5 += __shfl_xor(a5, m);
    a6 += __shfl_xor(a6, m); a7 += __shfl_xor(a7, m);
  }
  if (lane < 8){
    int c = lane << 3;
    sAgg[w][c+0]=a0; sAgg[w][c+1]=a1; sAgg[w][c+2]=a2; sAgg[w][c+3]=a3;
    sAgg[w][c+4]=a4; sAgg[w][c+5]=a5; sAgg[w][c+6]=a6; sAgg[w][c+7]=a7;
  }
  float acc = b[lane];
  #pragma unroll 8
  for (int k = 0; k < 64; ++k) acc += sAgg[w][k] * sW[k * 64 + lane];
  acc = (acc > 0.f) ? acc : SLOPE * acc;
  out[node * 64 + lane] = f2bf(acc);
}

// ---------------- Last layer: y = x @ W5 [N,3], then agg + b5 ----------------
__global__ void premult_k(const unsigned short* __restrict__ x, const float* __restrict__ W5,
                          float* __restrict__ y){
  int gt = blockIdx.x * 256 + threadIdx.x;
  int node = gt >> 6;
  int lane = threadIdx.x & 63;
  float xv = bf2f(x[node * 64 + lane]);
  float p0 = xv * W5[lane * 3 + 0];
  float p1 = xv * W5[lane * 3 + 1];
  float p2 = xv * W5[lane * 3 + 2];
  for (int m = 1; m < 64; m <<= 1){
    p0 += __shfl_xor(p0, m);
    p1 += __shfl_xor(p1, m);
    p2 += __shfl_xor(p2, m);
  }
  if (lane == 0){
    y[node * 3 + 0] = p0;
    y[node * 3 + 1] = p1;
    y[node * 3 + 2] = p2;
  }
}

__global__ void agg3_k(const float* __restrict__ y, const int* __restrict__ row_ptr,
                       const int* __restrict__ ssrc, const float* __restrict__ b5,
                       float* __restrict__ out){
  int gt = blockIdx.x * 256 + threadIdx.x;
  int node = gt >> 6;
  int lane = threadIdx.x & 63;
  int s = row_ptr[node], t = row_ptr[node + 1];
  int c = lane & 3;
  float acc = 0.f;
  if (c < 3){
    for (int i = s + (lane >> 2); i < t; i += 16) acc += y[(size_t)ssrc[i] * 3 + c];
  }
  for (int m = 4; m < 64; m <<= 1) acc += __shfl_xor(acc, m);
  if (lane < 3) out[node * 3 + lane] = acc + b5[lane];
}

// ---------------- launch ----------------

extern "C" void kernel_launch(void* const* d_in, const int* in_sizes, int n_in,
                              void* d_out, int out_size, void* d_ws, size_t ws_size,
                              hipStream_t stream){
  const float* feat = (const float*)d_in[0];
  const int*   src  = (const int*)d_in[1];
  const int*   dst  = (const int*)d_in[2];
  const float* W1   = (const float*)d_in[3];
  const float* b1   = (const float*)d_in[4];
  const float* W2   = (const float*)d_in[5];
  const float* b2   = (const float*)d_in[6];
  const float* W5   = (const float*)d_in[7];
  const float* b5   = (const float*)d_in[8];
  float* out = (float*)d_out;

  char* p = (char*)d_ws;
  auto carve = [&](size_t bytes) -> char* {
    char* r = p; p += align_up(bytes, 512); return r;
  };
  int*   counts  = (int*)carve((size_t)N_NODES * 4);
  int*   row_ptr = (int*)carve((size_t)(N_NODES + 1) * 4);
  int*   bsums   = (int*)carve(128 * 4);
  int*   ghist   = (int*)carve((size_t)NGH * 4);
  int*   goff    = (int*)carve((size_t)NGH * 4);
  int*   ssrc    = (int*)carve((size_t)N_EDGES * 4);
  unsigned short* bufA = (unsigned short*)carve((size_t)N_NODES * 64 * 2);
  unsigned short* bufB = (unsigned short*)carve((size_t)N_NODES * 64 * 2);
  float* y3      = (float*)carve((size_t)N_NODES * 3 * 4);
  int*   pk      = (int*)carve((size_t)N_EDGES * 4);

  // ---- CSR build ----
  gbhist_k<<<NBLK_B, 256, 0, stream>>>(dst, ghist);
  {
    int nb = (NGH + 1023) / 1024;  // 98
    scan1_k<<<nb, 256, 0, stream>>>(ghist, goff, bsums, NGH);
    scan2_k<<<1, 64, 0, stream>>>(bsums, nb);
    scan3_k<<<(NGH + 256) / 256, 256, 0, stream>>>(goff, bsums, NGH, 0);
  }
  passB_k<<<NBLK_B, 256, 0, stream>>>(src, dst, goff, pk);
  histnode_k<<<NBUCK, 256, 0, stream>>>(pk, goff, counts);
  {
    int nb = (N_NODES + 1023) / 1024;  // 98
    scan1_k<<<nb, 256, 0, stream>>>(counts, row_ptr, bsums, N_NODES);
    scan2_k<<<1, 64, 0, stream>>>(bsums, nb);
    scan3_k<<<(N_NODES + 256) / 256, 256, 0, stream>>>(row_ptr, bsums, N_NODES, 1);
  }
  passC_k<<<NBUCK, 256, 0, stream>>>(pk, goff, row_ptr, ssrc);

  // ---- layers ----
  conv1_k<<<(N_NODES * 64) / 256, 256, 0, stream>>>(feat, row_ptr, ssrc, W1, b1, bufA);

  unsigned short* xin = bufA;
  unsigned short* xout = bufB;
  for (int l = 0; l < 7; ++l){
    conv64_k<<<N_NODES / 4, 256, 0, stream>>>(xin, row_ptr, ssrc, W2, b2, xout);
    unsigned short* tmp = xin; xin = xout; xout = tmp;
  }

  premult_k<<<(N_NODES * 64) / 256, 256, 0, stream>>>(xin, W5, y3);
  agg3_k<<<(N_NODES * 64) / 256, 256, 0, stream>>>(y3, row_ptr, ssrc, b5, out);
}

// Round 4
// 620.659 us; speedup vs baseline: 2.4835x; 1.5408x over previous
//
#include <hip/hip_runtime.h>

#define N_NODES 100000
#define N_EDGES 3200000
#define SLOPE 0.01f

#define NBUCK 391              // ceil(100000/256) buckets of 256 dst nodes
#define NBLK_B 256             // one cursor-group per block: exclusive append regions
#define EPB (N_EDGES / NBLK_B) // 12500 edges per block (exact)
#define NGH (NBUCK * NBLK_B)   // ghist/goff size = 100096

typedef __attribute__((ext_vector_type(8))) short short8;
typedef __attribute__((ext_vector_type(4))) float f32x4;

static inline size_t align_up(size_t x, size_t a){ return (x + a - 1) / a * a; }

__device__ inline unsigned short f2bf(float f){
  unsigned u = __float_as_uint(f);
  u += 0x7fffu + ((u >> 16) & 1u);
  return (unsigned short)(u >> 16);
}
__device__ inline float bf2f(unsigned short s){
  return __uint_as_float(((unsigned)s) << 16);
}
__device__ inline void add2(float& a0, float& a1, unsigned u){
  a0 += __uint_as_float(u << 16);
  a1 += __uint_as_float(u & 0xffff0000u);
}

// ---------------- CSR build: per-block exclusive bucketed 2-pass ----------------

__global__ void gbhist_k(const int* __restrict__ dst, int* __restrict__ ghist){
  __shared__ int h[NBUCK];
  int tid = threadIdx.x, blk = blockIdx.x;
  for (int i = tid; i < NBUCK; i += 256) h[i] = 0;
  __syncthreads();
  int e0 = blk * EPB;
  for (int e = e0 + tid; e < e0 + EPB; e += 256) atomicAdd(&h[dst[e] >> 8], 1);
  __syncthreads();
  for (int i = tid; i < NBUCK; i += 256) ghist[i * NBLK_B + blk] = h[i];
}

__global__ void scan1_k(const int* __restrict__ in, int* __restrict__ out,
                        int* __restrict__ bsums, int n){
  __shared__ int lds[256];
  int tid = threadIdx.x;
  int base = blockIdx.x * 1024 + tid * 4;
  int v0 = (base + 0 < n) ? in[base + 0] : 0;
  int v1 = (base + 1 < n) ? in[base + 1] : 0;
  int v2 = (base + 2 < n) ? in[base + 2] : 0;
  int v3 = (base + 3 < n) ? in[base + 3] : 0;
  int tsum = v0 + v1 + v2 + v3;
  lds[tid] = tsum;
  for (int off = 1; off < 256; off <<= 1){
    __syncthreads();
    int x = (tid >= off) ? lds[tid - off] : 0;
    __syncthreads();
    lds[tid] += x;
  }
  __syncthreads();
  int excl = lds[tid] - tsum;
  if (base + 0 < n) out[base + 0] = excl;
  if (base + 1 < n) out[base + 1] = excl + v0;
  if (base + 2 < n) out[base + 2] = excl + v0 + v1;
  if (base + 3 < n) out[base + 3] = excl + v0 + v1 + v2;
  if (tid == 255) bsums[blockIdx.x] = lds[255];
}

__global__ void scan2_k(int* bsums, int nb){
  if (threadIdx.x == 0 && blockIdx.x == 0){
    int acc = 0;
    for (int i = 0; i < nb; i++){ int t = bsums[i]; bsums[i] = acc; acc += t; }
  }
}

__global__ void scan3_k(int* __restrict__ out, const int* __restrict__ bsums,
                        int n, int set_end){
  int i = blockIdx.x * 256 + threadIdx.x;
  if (i < n) out[i] += bsums[i >> 10];
  else if (i == n && set_end) out[n] = N_EDGES;
}

__global__ void passB_k(const int* __restrict__ src, const int* __restrict__ dst,
                        const int* __restrict__ goff, int* __restrict__ pk){
  __shared__ int cur[NBUCK];
  int tid = threadIdx.x, blk = blockIdx.x;
  for (int b = tid; b < NBUCK; b += 256) cur[b] = goff[b * NBLK_B + blk];
  __syncthreads();
  int e0 = blk * EPB;
  for (int e = e0 + tid; e < e0 + EPB; e += 256){
    int d = dst[e];
    int pos = atomicAdd(&cur[d >> 8], 1);
    pk[pos] = (src[e] << 8) | (d & 255);
  }
}

__global__ void histnode_k(const int* __restrict__ pk, const int* __restrict__ goff,
                           int* __restrict__ counts){
  __shared__ int cnt[256];
  int b = blockIdx.x, tid = threadIdx.x;
  cnt[tid] = 0;
  __syncthreads();
  int s = goff[b * NBLK_B];
  int e = (b == NBUCK - 1) ? N_EDGES : goff[(b + 1) * NBLK_B];
  for (int i = s + tid; i < e; i += 256) atomicAdd(&cnt[pk[i] & 255], 1);
  __syncthreads();
  int node = b * 256 + tid;
  if (node < N_NODES) counts[node] = cnt[tid];
}

__global__ void passC_k(const int* __restrict__ pk, const int* __restrict__ goff,
                        const int* __restrict__ row_ptr, int* __restrict__ ssrc){
  __shared__ int cur[256];
  int b = blockIdx.x, tid = threadIdx.x;
  int node = b * 256 + tid;
  if (node < N_NODES) cur[tid] = row_ptr[node];
  __syncthreads();
  int s = goff[b * NBLK_B];
  int e = (b == NBUCK - 1) ? N_EDGES : goff[(b + 1) * NBLK_B];
  for (int i = s + tid; i < e; i += 256){
    int v = pk[i];
    int p = atomicAdd(&cur[v & 255], 1);
    ssrc[p] = v >> 8;
  }
}

// ---------------- Layer 1: feat[N,4] -> lrelu(agg @ W1 + b1) -> bf16 [N,64] --------
__global__ void conv1_k(const float* __restrict__ feat, const int* __restrict__ row_ptr,
                        const int* __restrict__ ssrc, const float* __restrict__ W1,
                        const float* __restrict__ b1, unsigned short* __restrict__ out){
  int gt = blockIdx.x * 256 + threadIdx.x;
  int node = gt >> 6;
  int lane = threadIdx.x & 63;
  int s = row_ptr[node], t = row_ptr[node + 1];
  float a0 = 0.f, a1 = 0.f, a2 = 0.f, a3 = 0.f;
  for (int i = s + lane; i < t; i += 64){
    int nb = ssrc[i];
    const float4 v = *(const float4*)(feat + (size_t)nb * 4);
    a0 += v.x; a1 += v.y; a2 += v.z; a3 += v.w;
  }
  for (int m = 1; m < 64; m <<= 1){
    a0 += __shfl_xor(a0, m);
    a1 += __shfl_xor(a1, m);
    a2 += __shfl_xor(a2, m);
    a3 += __shfl_xor(a3, m);
  }
  float o = b1[lane] + a0 * W1[lane] + a1 * W1[64 + lane] + a2 * W1[128 + lane] + a3 * W1[192 + lane];
  o = (o > 0.f) ? o : SLOPE * o;
  out[node * 64 + lane] = f2bf(o);
}

// ---------------- Dense GEMM: z[N,64] = x[N,64] @ W[64,64] (bf16 in/out, MFMA) ------
// one wave per 16-node tile, grid-stride. A/B share the same assumed k-mapping, so
// any in-fragment k permutation cancels.
__global__ void mm64_k(const unsigned short* __restrict__ x, const float* __restrict__ W,
                       unsigned short* __restrict__ z){
  int lane = threadIdx.x & 63;
  int wid = (blockIdx.x * blockDim.x + threadIdx.x) >> 6;
  int nwaves = (gridDim.x * blockDim.x) >> 6;
  int r = lane & 15, g = lane >> 4;
  short8 Bf[4][2];
  #pragma unroll
  for (int nc = 0; nc < 4; ++nc)
    #pragma unroll
    for (int kt = 0; kt < 2; ++kt){
      short8 f;
      #pragma unroll
      for (int j = 0; j < 8; ++j){
        int k = kt * 32 + g * 8 + j;
        f[j] = (short)f2bf(W[k * 64 + nc * 16 + r]);
      }
      Bf[nc][kt] = f;
    }
  const int NT = N_NODES / 16;  // 6250
  for (int t = wid; t < NT; t += nwaves){
    int base = t * 16;
    const short8 A0 = *(const short8*)(x + (size_t)(base + r) * 64 + g * 8);
    const short8 A1 = *(const short8*)(x + (size_t)(base + r) * 64 + 32 + g * 8);
    #pragma unroll
    for (int nc = 0; nc < 4; ++nc){
      f32x4 c = {0.f, 0.f, 0.f, 0.f};
      c = __builtin_amdgcn_mfma_f32_16x16x32_bf16(A0, Bf[nc][0], c, 0, 0, 0);
      c = __builtin_amdgcn_mfma_f32_16x16x32_bf16(A1, Bf[nc][1], c, 0, 0, 0);
      #pragma unroll
      for (int i = 0; i < 4; ++i){
        int row = g * 4 + i;   // C/D: col=lane&15, row=(lane>>4)*4+i  [verified layout]
        z[(size_t)(base + row) * 64 + nc * 16 + r] = f2bf(c[i]);
      }
    }
  }
}

// ---------------- Mid-layer aggregate: x' = lrelu(agg(z) + b) -> bf16 ----------------
// one wave per node; lane = (slot q = lane>>3, chunk o = lane&7). 6 gathers in flight.
__global__ void agg64_k(const unsigned short* __restrict__ z, const int* __restrict__ row_ptr,
                        const int* __restrict__ ssrc, const float* __restrict__ b,
                        unsigned short* __restrict__ out){
  int gt = blockIdx.x * 256 + threadIdx.x;
  int node = gt >> 6;
  int lane = threadIdx.x & 63;
  int s = row_ptr[node], cnt = row_ptr[node + 1] - s;
  int nb_l = ssrc[s + lane];          // coalesced; 64-int margin past N_EDGES is zeroed
  int q = lane >> 3, o = lane & 7;
  float a0=0.f,a1=0.f,a2=0.f,a3=0.f,a4=0.f,a5=0.f,a6=0.f,a7=0.f;
  uint4 v0, v1, v2, v3, v4, v5;
  int cm1 = (cnt > 0) ? cnt - 1 : 0;
  {
    int j0 = min( 0 + q, cm1), j1 = min( 8 + q, cm1), j2 = min(16 + q, cm1);
    int j3 = min(24 + q, cm1), j4 = min(32 + q, cm1), j5 = min(40 + q, cm1);
    int n0 = __shfl(nb_l, j0), n1 = __shfl(nb_l, j1), n2 = __shfl(nb_l, j2);
    int n3 = __shfl(nb_l, j3), n4 = __shfl(nb_l, j4), n5 = __shfl(nb_l, j5);
    const size_t oo = (size_t)(o << 3);
    v0 = *(const uint4*)(z + (size_t)n0 * 64 + oo);
    v1 = *(const uint4*)(z + (size_t)n1 * 64 + oo);
    v2 = *(const uint4*)(z + (size_t)n2 * 64 + oo);
    v3 = *(const uint4*)(z + (size_t)n3 * 64 + oo);
    v4 = *(const uint4*)(z + (size_t)n4 * 64 + oo);
    v5 = *(const uint4*)(z + (size_t)n5 * 64 + oo);
  }
  if ( 0 + q < cnt){ add2(a0,a1,v0.x); add2(a2,a3,v0.y); add2(a4,a5,v0.z); add2(a6,a7,v0.w); }
  if ( 8 + q < cnt){ add2(a0,a1,v1.x); add2(a2,a3,v1.y); add2(a4,a5,v1.z); add2(a6,a7,v1.w); }
  if (16 + q < cnt){ add2(a0,a1,v2.x); add2(a2,a3,v2.y); add2(a4,a5,v2.z); add2(a6,a7,v2.w); }
  if (24 + q < cnt){ add2(a0,a1,v3.x); add2(a2,a3,v3.y); add2(a4,a5,v3.z); add2(a6,a7,v3.w); }
  if (32 + q < cnt){ add2(a0,a1,v4.x); add2(a2,a3,v4.y); add2(a4,a5,v4.z); add2(a6,a7,v4.w); }
  if (40 + q < cnt){ add2(a0,a1,v5.x); add2(a2,a3,v5.y); add2(a4,a5,v5.z); add2(a6,a7,v5.w); }
  // rare tail (deg > 48): Poisson(32) => ~0.3% of nodes
  for (int i = 48 + q; i < cnt; i += 8){
    int nb = ssrc[s + i];
    uint4 vv = *(const uint4*)(z + (size_t)nb * 64 + (size_t)(o << 3));
    add2(a0,a1,vv.x); add2(a2,a3,vv.y); add2(a4,a5,vv.z); add2(a6,a7,vv.w);
  }
  // reduce over slots (xor bits 3,4,5)
  for (int m = 8; m < 64; m <<= 1){
    a0 += __shfl_xor(a0, m); a1 += __shfl_xor(a1, m);
    a2 += __shfl_xor(a2, m); a3 += __shfl_xor(a3, m);
    a4 += __shfl_xor(a4, m); a5 += __shfl_xor(a5, m);
    a6 += __shfl_xor(a6, m); a7 += __shfl_xor(a7, m);
  }
  if (lane < 8){
    const float4 bA = *(const float4*)(b + lane * 8);
    const float4 bB = *(const float4*)(b + lane * 8 + 4);
    float y0 = a0 + bA.x, y1 = a1 + bA.y, y2 = a2 + bA.z, y3 = a3 + bA.w;
    float y4 = a4 + bB.x, y5 = a5 + bB.y, y6 = a6 + bB.z, y7 = a7 + bB.w;
    y0 = (y0 > 0.f) ? y0 : SLOPE * y0;  y1 = (y1 > 0.f) ? y1 : SLOPE * y1;
    y2 = (y2 > 0.f) ? y2 : SLOPE * y2;  y3 = (y3 > 0.f) ? y3 : SLOPE * y3;
    y4 = (y4 > 0.f) ? y4 : SLOPE * y4;  y5 = (y5 > 0.f) ? y5 : SLOPE * y5;
    y6 = (y6 > 0.f) ? y6 : SLOPE * y6;  y7 = (y7 > 0.f) ? y7 : SLOPE * y7;
    uint4 pkd;
    pkd.x = (unsigned)f2bf(y0) | ((unsigned)f2bf(y1) << 16);
    pkd.y = (unsigned)f2bf(y2) | ((unsigned)f2bf(y3) << 16);
    pkd.z = (unsigned)f2bf(y4) | ((unsigned)f2bf(y5) << 16);
    pkd.w = (unsigned)f2bf(y6) | ((unsigned)f2bf(y7) << 16);
    *(uint4*)(out + (size_t)node * 64 + lane * 8) = pkd;
  }
}

// ---------------- Last layer: y = x @ W5 [N,3], then agg + b5 ----------------
__global__ void premult_k(const unsigned short* __restrict__ x, const float* __restrict__ W5,
                          float* __restrict__ y){
  int gt = blockIdx.x * 256 + threadIdx.x;
  int node = gt >> 6;
  int lane = threadIdx.x & 63;
  float xv = bf2f(x[node * 64 + lane]);
  float p0 = xv * W5[lane * 3 + 0];
  float p1 = xv * W5[lane * 3 + 1];
  float p2 = xv * W5[lane * 3 + 2];
  for (int m = 1; m < 64; m <<= 1){
    p0 += __shfl_xor(p0, m);
    p1 += __shfl_xor(p1, m);
    p2 += __shfl_xor(p2, m);
  }
  if (lane == 0){
    y[node * 3 + 0] = p0;
    y[node * 3 + 1] = p1;
    y[node * 3 + 2] = p2;
  }
}

__global__ void agg3_k(const float* __restrict__ y, const int* __restrict__ row_ptr,
                       const int* __restrict__ ssrc, const float* __restrict__ b5,
                       float* __restrict__ out){
  int gt = blockIdx.x * 256 + threadIdx.x;
  int node = gt >> 6;
  int lane = threadIdx.x & 63;
  int s = row_ptr[node], t = row_ptr[node + 1];
  int c = lane & 3;
  float acc = 0.f;
  if (c < 3){
    for (int i = s + (lane >> 2); i < t; i += 16) acc += y[(size_t)ssrc[i] * 3 + c];
  }
  for (int m = 4; m < 64; m <<= 1) acc += __shfl_xor(acc, m);
  if (lane < 3) out[node * 3 + lane] = acc + b5[lane];
}

// ---------------- launch ----------------

extern "C" void kernel_launch(void* const* d_in, const int* in_sizes, int n_in,
                              void* d_out, int out_size, void* d_ws, size_t ws_size,
                              hipStream_t stream){
  const float* feat = (const float*)d_in[0];
  const int*   src  = (const int*)d_in[1];
  const int*   dst  = (const int*)d_in[2];
  const float* W1   = (const float*)d_in[3];
  const float* b1   = (const float*)d_in[4];
  const float* W2   = (const float*)d_in[5];
  const float* b2   = (const float*)d_in[6];
  const float* W5   = (const float*)d_in[7];
  const float* b5   = (const float*)d_in[8];
  float* out = (float*)d_out;

  char* p = (char*)d_ws;
  auto carve = [&](size_t bytes) -> char* {
    char* r = p; p += align_up(bytes, 512); return r;
  };
  int*   counts  = (int*)carve((size_t)N_NODES * 4);
  int*   row_ptr = (int*)carve((size_t)(N_NODES + 1) * 4);
  int*   bsums   = (int*)carve(128 * 4);
  int*   ghist   = (int*)carve((size_t)NGH * 4);
  int*   goff    = (int*)carve((size_t)NGH * 4);
  int*   ssrc    = (int*)carve(((size_t)N_EDGES + 64) * 4);  // +64 margin for coalesced read
  unsigned short* bufA = (unsigned short*)carve((size_t)N_NODES * 64 * 2);
  unsigned short* bufB = (unsigned short*)carve((size_t)N_NODES * 64 * 2);
  float* y3      = (float*)carve((size_t)N_NODES * 3 * 4);
  int*   pk      = (int*)carve((size_t)N_EDGES * 4);
  // z buffer aliases pk: pk is dead once passC completes (before any conv)
  unsigned short* zbuf = (unsigned short*)pk;

  // ---- CSR build ----
  gbhist_k<<<NBLK_B, 256, 0, stream>>>(dst, ghist);
  {
    int nb = (NGH + 1023) / 1024;  // 98
    scan1_k<<<nb, 256, 0, stream>>>(ghist, goff, bsums, NGH);
    scan2_k<<<1, 64, 0, stream>>>(bsums, nb);
    scan3_k<<<(NGH + 256) / 256, 256, 0, stream>>>(goff, bsums, NGH, 0);
  }
  passB_k<<<NBLK_B, 256, 0, stream>>>(src, dst, goff, pk);
  histnode_k<<<NBUCK, 256, 0, stream>>>(pk, goff, counts);
  {
    int nb = (N_NODES + 1023) / 1024;  // 98
    scan1_k<<<nb, 256, 0, stream>>>(counts, row_ptr, bsums, N_NODES);
    scan2_k<<<1, 64, 0, stream>>>(bsums, nb);
    scan3_k<<<(N_NODES + 256) / 256, 256, 0, stream>>>(row_ptr, bsums, N_NODES, 1);
  }
  passC_k<<<NBUCK, 256, 0, stream>>>(pk, goff, row_ptr, ssrc);
  hipMemsetAsync(ssrc + N_EDGES, 0, 64 * 4, stream);  // margin for agg64's coalesced read

  // ---- layers ----
  conv1_k<<<(N_NODES * 64) / 256, 256, 0, stream>>>(feat, row_ptr, ssrc, W1, b1, bufA);

  unsigned short* xin = bufA;
  unsigned short* xout = bufB;
  for (int l = 0; l < 7; ++l){
    mm64_k<<<256, 256, 0, stream>>>(xin, W2, zbuf);
    agg64_k<<<(N_NODES * 64) / 256, 256, 0, stream>>>(zbuf, row_ptr, ssrc, b2, xout);
    unsigned short* tmp = xin; xin = xout; xout = tmp;
  }

  premult_k<<<(N_NODES * 64) / 256, 256, 0, stream>>>(xin, W5, y3);
  agg3_k<<<(N_NODES * 64) / 256, 256, 0, stream>>>(y3, row_ptr, ssrc, b5, out);
}